// Round 11
// baseline (299.847 us; speedup 1.0000x reference)
//
#include <hip/hip_runtime.h>
#include <hip/hip_bf16.h>
#include <math.h>

#define BB   64
#define TT   32
#define CC   256
#define KK   16384
#define G1c  4.0f
#define G2c  5.0f
#define G3c  10.0f
#define INV_T 20.0f
#define EPSF 1e-8f

// Workspace layout (floats)
#define WS_SIM 0
#define WS_S0  4096
#define WS_S2  8192
#define WS_CN  12288
#define WS_RN  28672
#define WS_CAN 45056
#define WS_RAN 61440
#define WS_QN  77824
#define WS_PM  79872                 // [2][128 ch][64 row]
#define WS_PS  (WS_PM + 16384)
#define WS_CNT  (WS_PS + 16384)      // reused: [2][64] moco diag dots
#define WS_RNT  (WS_CNT + 16384)
#define WS_CANT (WS_RNT + 16384)
#define WS_RANT (WS_CANT + 16384)
#define WS_F32_TOTAL (WS_RANT + 16384)
#define WS_DOT  WS_CNT               // dot_it[64] then dot_ti[64]

// bf16 arrays (shorts), after the f32 section
// ctxT layout: [j][tile(10)][8192 shorts]; swizzled subtiles (see swz13).
#define CTXT_ELEMS (64*320*256)
#define WQ_ELEMS   (64*32*256)     // wq[i][t][c]
#define WQ_OFF     CTXT_ELEMS
#define CNRN_OFF   (CTXT_ELEMS + WQ_ELEMS)   // [2][64][256]

typedef __attribute__((ext_vector_type(8))) short short8;
typedef __attribute__((ext_vector_type(4))) short short4v;
typedef __attribute__((ext_vector_type(4))) float float4v;

__device__ __forceinline__ float4v mfma_bf16(short8 a, short8 b, float4v c) {
    return __builtin_amdgcn_mfma_f32_16x16x32_bf16(a, b, c, 0, 0, 0);
}

__device__ __forceinline__ short f2bf(float f) {
    union { float f; unsigned u; } x; x.f = f;
    unsigned r = x.u + 0x7FFFu + ((x.u >> 16) & 1u);
    return (short)(r >> 16);
}

// involutive swizzle on 13-bit tile-local short index
__device__ __forceinline__ int swz13(int L) {
    return L ^ (((L>>10)&3)<<4) ^ ((((L>>6)&1) ^ ((L>>10)&1))<<3);
}

// async global->LDS: one wave stages 4KB (4 calls x 64 lanes x 16B).
__device__ __forceinline__ void stage_tile(const short* g, short* l) {
    #pragma unroll
    for (int m = 0; m < 4; m++)
        __builtin_amdgcn_global_load_lds(
            (const __attribute__((address_space(1))) unsigned int*)(g + m*512),
            (__attribute__((address_space(3))) unsigned int*)(l + m*512),
            16, 0, 0);
}

// ---------------------------------------------------------------------------
// Prep. grid: [0,256) codes | [256,320) qn | [320,1600) ctxT | [1600,1664) wq
// (identical to R9)
// ---------------------------------------------------------------------------
__global__ __launch_bounds__(256) void prep_kernel(
    const float* __restrict__ cnn, const float* __restrict__ rnn,
    const float* __restrict__ img, const float* __restrict__ wemb,
    const float* __restrict__ cnnA, const float* __restrict__ rnnA,
    float* __restrict__ W)
{
    int bid = blockIdx.x, tid = threadIdx.x;
    short* B16 = (short*)(W + WS_F32_TOTAL);
    short* ctxT = B16;
    short* wq   = B16 + WQ_OFF;
    short* cnrn = B16 + CNRN_OFF;

    if (bid < 256) {
        int mat = bid >> 6, row = bid & 63;
        const float* src = (mat==0)? cnn : (mat==1)? rnn : (mat==2)? cnnA : rnnA;
        float* dst  = W + ((mat==0)? WS_CN  : (mat==1)? WS_RN  : (mat==2)? WS_CAN  : WS_RAN);
        float v = src[row*256 + tid];
        float ss = v*v;
        for (int o=1;o<64;o<<=1) ss += __shfl_xor(ss,o);
        __shared__ float sc[4];
        if ((tid&63)==0) sc[tid>>6] = ss;
        __syncthreads();
        float tot = sc[0]+sc[1]+sc[2]+sc[3];
        float inv = 1.0f / fmaxf(sqrtf(tot), EPSF);
        float nv = v*inv;
        dst[row*256+tid] = nv;
        if (mat < 2) cnrn[(mat*64+row)*256 + tid] = f2bf(nv);
    } else if (bid < 320) {
        int i = bid - 256;
        int t = tid >> 3, k = tid & 7;
        const float4* wp = (const float4*)(wemb + (i*32 + t)*256 + k*32);
        float ss = 0.f;
        #pragma unroll
        for (int c4=0;c4<8;c4++){
            float4 v = wp[c4];
            ss += v.x*v.x + v.y*v.y + v.z*v.z + v.w*v.w;
        }
        ss += __shfl_xor(ss,1); ss += __shfl_xor(ss,2); ss += __shfl_xor(ss,4);
        if (k==0) W[WS_QN + i*32 + t] = sqrtf(ss);
    } else if (bid < 1600) {
        int b3 = bid - 320; int j = b3 / 20, mt20 = b3 % 20;
        int half = mt20 & 1;
        int s0 = mt20 * 16;
        __shared__ float tbuf[16*257];
        #pragma unroll
        for (int it=0; it<16; it++) {
            int idx = tid + it*256;
            int c = idx >> 4, sl = idx & 15, s = s0 + sl;
            float v = (s < 289) ? img[((size_t)(j*256 + c))*289 + s] : 0.0f;
            tbuf[sl*257 + c] = v;
        }
        __syncthreads();
        short* dst = ctxT + (size_t)j*81920 + (size_t)mt20*4096;
        #pragma unroll
        for (int it=0; it<4; it++) {
            int idx4 = tid + it*256;
            int v = half*4096 + idx4*4;
            int L = swz13(v);
            int sl = ((L>>10)&3)*4 + ((L>>4)&3);
            int c  = ((L>>6)&15)*16 + (L&15);
            const float* tb = &tbuf[sl*257 + c];
            short4v o = { f2bf(tb[0]), f2bf(tb[1]), f2bf(tb[2]), f2bf(tb[3]) };
            *(short4v*)(dst + idx4*4) = o;
        }
    } else {
        const float4* src4 = (const float4*)wemb;
        for (int idx = (bid-1600)*256 + tid; idx < WQ_ELEMS/4; idx += 64*256) {
            float4 v = src4[idx];
            short4v o = { f2bf(v.x), f2bf(v.y), f2bf(v.z), f2bf(v.w) };
            *(short4v*)(wq + idx*4) = o;
        }
    }
}

// ---------------------------------------------------------------------------
// Fused moco + smat + attn.
// R11: occupancy unlock — 3 blocks/CU.
//  - ctx back to 2 buffers (LDS ~51 KB -> 3 blocks fit in 160 KB)
//  - bq no longer persistent: reloaded per tile per t-half from L2-hot wq
//    (designed reload vs the compiler's scratch spill of R2/R4)
//  - tr-reads split 2+2 (16 transient regs), R4's proven barrier discipline
//  - moco: afr streamed (R4 version)
//  - __launch_bounds__(256, 3)
// Tripwire: WRITE_SIZE >> 0.2 MB = spills -> revert.
// ---------------------------------------------------------------------------
__global__ __launch_bounds__(256, 3) void attn_moco_kernel(
    const float* __restrict__ queue, const float* __restrict__ queueIm,
    float* __restrict__ W)
{
    __shared__ __align__(16) short ctx_sc[2][8192];         // 32 KB (dbuf)
    __shared__ __align__(16) short eTile[2][2][32][40];     // 10240 B (dbuf)
    __shared__ float Dp[4][32], Np[4][32];
    __shared__ float wn2P[4][2][2][16];
    __shared__ float redm[4][64], reds[4][64];     // moco
    __shared__ float sa0[256], sa1[256];           // smat
    __shared__ float part[2][64][4];
    __shared__ float dred[2][4];

    int bid = blockIdx.x, tid = threadIdx.x;
    int lane = tid & 63, wave = tid >> 6;
    int lo16 = lane & 15, quad = lane >> 4;

    const short* B16 = (const short*)(W + WS_F32_TOTAL);

    if (bid >= 320) {
        // ================= attention =================
        const short* ctxT = B16;
        const short* wq   = B16 + WQ_OFF;

        int abid0 = bid - 320;
        int abid = (abid0 & 7)*256 + (abid0 >> 3);   // XCD swizzle
        int j = abid >> 5, ip = abid & 31;
        int i_l = wave >> 1, mt = wave & 1;
        int i_g = ip*2 + i_l;

        float4v wacc[4][4];
        #pragma unroll
        for (int cm=0;cm<4;cm++)
            #pragma unroll
            for (int cb2=0;cb2<4;cb2++) wacc[cm][cb2] = (float4v){0.f,0.f,0.f,0.f};
        float D8[8], N8[8];
        #pragma unroll
        for (int u=0;u<8;u++){ D8[u]=0.f; N8[u]=0.f; }

        const short* ctxTj = ctxT + (size_t)j * 81920;
        const short* pq = wq + i_g*8192;

        int s4p = lo16 >> 2;
        int qh = quad >> 1, ql = quad & 1;
        int Lb = (mt*4 + s4p)*1024 + qh*64
               + (((lo16&3) ^ s4p) << 4)
               + ((ql ^ qh ^ (s4p&1)) << 3);
        int pcol = mt*16 + (lo16 & 12) + ((lo16 & 3) ^ s4p);
        unsigned trbase = (unsigned)(unsigned long long)(const void*)(&ctx_sc[0][0])
                        + (unsigned)(quad*4096 + wave*512 + lo16*2);

        // prologue: stage tiles 0,1 into both buffers
        stage_tile(ctxTj + 0*8192 + wave*2048 + lane*8, &ctx_sc[0][wave*2048]);
        stage_tile(ctxTj + 1*8192 + wave*2048 + lane*8, &ctx_sc[1][wave*2048]);
        __syncthreads();

        for (int tile = 0; tile < 10; tile++) {
            int cur = tile & 1;
            const short* score_base = &ctx_sc[cur][0] + Lb;

            // scores half 0: reload bq (t-half 0) from L2-hot wq, MFMA vs LDS ctx
            float4v a0 = {0.f,0.f,0.f,0.f}, a1 = {0.f,0.f,0.f,0.f};
            {
                short8 bqt[8];
                #pragma unroll
                for (int kk=0;kk<8;kk++)
                    bqt[kk] = *(const short8*)(pq + lo16*256 + kk*32 + quad*8);
                #pragma unroll
                for (int kk=0;kk<8;kk++) {
                    short8 cf = *(const short8*)(score_base + kk*128);
                    a0 = mfma_bf16(bqt[kk], cf, a0);
                }
                // scores half 1
                #pragma unroll
                for (int kk=0;kk<8;kk++)
                    bqt[kk] = *(const short8*)(pq + (16+lo16)*256 + kk*32 + quad*8);
                #pragma unroll
                for (int kk=0;kk<8;kk++) {
                    short8 cf = *(const short8*)(score_base + kk*128);
                    a1 = mfma_bf16(bqt[kk], cf, a1);
                }
            }

            // tr batch 1 (cm 0,1)
            unsigned trA = trbase + (unsigned)(cur*16384);
            unsigned trB = trA ^ 16u;
            short4v w00,w01,w10,w11;
            asm volatile("ds_read_b64_tr_b16 %0, %1 offset:0"    : "=v"(w00) : "v"(trA));
            asm volatile("ds_read_b64_tr_b16 %0, %1 offset:2048" : "=v"(w01) : "v"(trB));
            asm volatile("ds_read_b64_tr_b16 %0, %1 offset:128"  : "=v"(w10) : "v"(trB));
            asm volatile("ds_read_b64_tr_b16 %0, %1 offset:2176" : "=v"(w11) : "v"(trA));

            // softmax over t (in-register + 2 shfl); writes eTile[cur]
            {
                float mx = fmaxf(fmaxf(fmaxf(a0[0],a0[1]), fmaxf(a0[2],a0[3])),
                                 fmaxf(fmaxf(a1[0],a1[1]), fmaxf(a1[2],a1[3])));
                mx = fmaxf(mx, __shfl_xor(mx,16));
                mx = fmaxf(mx, __shfl_xor(mx,32));
                float e0[4], e1[4]; float z = 0.f;
                #pragma unroll
                for (int r=0;r<4;r++) {
                    e0[r] = __expf(a0[r]-mx); e1[r] = __expf(a1[r]-mx);
                    z += e0[r] + e1[r];
                }
                z += __shfl_xor(z,16); z += __shfl_xor(z,32);
                float grinv = G1c / z;
                int sg = tile*32 + mt*16 + lo16;
                short* et = &eTile[cur][i_l][0][0];
                #pragma unroll
                for (int r=0;r<4;r++) {
                    float ev0 = __expf(e0[r]*grinv);
                    float ev1 = __expf(e1[r]*grinv);
                    if (sg < 289) {
                        D8[r]   += ev0; N8[r]   += ev0*a0[r];
                        D8[4+r] += ev1; N8[4+r] += ev1*a1[r];
                    }
                    et[(quad*4+r)*40 + pcol]    = f2bf(ev0);
                    et[(16+quad*4+r)*40 + pcol] = f2bf(ev1);
                }
            }
            __syncthreads();                 // eTile visible; scores+tr1 drained;
                                             // stage(tile+1) landed (vmcnt drain)
            __builtin_amdgcn_sched_barrier(0);

            // wC half 1: cm 0,1
            short8 wa0_ = {w00[0],w00[1],w00[2],w00[3], w01[0],w01[1],w01[2],w01[3]};
            short8 wa1_ = {w10[0],w10[1],w10[2],w10[3], w11[0],w11[1],w11[2],w11[3]};
            const short8 bf00 = *(const short8*)&eTile[cur][0][lo16][quad*8];
            const short8 bf01 = *(const short8*)&eTile[cur][0][16+lo16][quad*8];
            const short8 bf10 = *(const short8*)&eTile[cur][1][lo16][quad*8];
            const short8 bf11 = *(const short8*)&eTile[cur][1][16+lo16][quad*8];
            wacc[0][0] = mfma_bf16(wa0_, bf00, wacc[0][0]);
            wacc[0][1] = mfma_bf16(wa0_, bf01, wacc[0][1]);
            wacc[0][2] = mfma_bf16(wa0_, bf10, wacc[0][2]);
            wacc[0][3] = mfma_bf16(wa0_, bf11, wacc[0][3]);
            wacc[1][0] = mfma_bf16(wa1_, bf00, wacc[1][0]);
            wacc[1][1] = mfma_bf16(wa1_, bf01, wacc[1][1]);
            wacc[1][2] = mfma_bf16(wa1_, bf10, wacc[1][2]);
            wacc[1][3] = mfma_bf16(wa1_, bf11, wacc[1][3]);

            // tr batch 2 (cm 2,3); explicit drain before DMA overwrite of ctx[cur]
            short4v w20,w21,w30,w31;
            asm volatile("ds_read_b64_tr_b16 %0, %1 offset:256"  : "=v"(w20) : "v"(trA));
            asm volatile("ds_read_b64_tr_b16 %0, %1 offset:2304" : "=v"(w21) : "v"(trB));
            asm volatile("ds_read_b64_tr_b16 %0, %1 offset:384"  : "=v"(w30) : "v"(trB));
            asm volatile("ds_read_b64_tr_b16 %0, %1 offset:2432" : "=v"(w31) : "v"(trA));
            asm volatile("s_waitcnt lgkmcnt(0)");
            __builtin_amdgcn_sched_barrier(0);
            if (tile < 8)
                stage_tile(ctxTj + (tile+2)*8192 + wave*2048 + lane*8,
                           &ctx_sc[cur][wave*2048]);

            short8 wa2_ = {w20[0],w20[1],w20[2],w20[3], w21[0],w21[1],w21[2],w21[3]};
            short8 wa3_ = {w30[0],w30[1],w30[2],w30[3], w31[0],w31[1],w31[2],w31[3]};
            wacc[2][0] = mfma_bf16(wa2_, bf00, wacc[2][0]);
            wacc[2][1] = mfma_bf16(wa2_, bf01, wacc[2][1]);
            wacc[2][2] = mfma_bf16(wa2_, bf10, wacc[2][2]);
            wacc[2][3] = mfma_bf16(wa2_, bf11, wacc[2][3]);
            wacc[3][0] = mfma_bf16(wa3_, bf00, wacc[3][0]);
            wacc[3][1] = mfma_bf16(wa3_, bf01, wacc[3][1]);
            wacc[3][2] = mfma_bf16(wa3_, bf10, wacc[3][2]);
            wacc[3][3] = mfma_bf16(wa3_, bf11, wacc[3][3]);
            // staged buffer fenced by NEXT iteration's __syncthreads
        }

        // D/N reduce + publish
        #pragma unroll
        for (int u=0;u<8;u++) {
            float d = D8[u], n = N8[u];
            d += __shfl_xor(d,1); d += __shfl_xor(d,2);
            d += __shfl_xor(d,4); d += __shfl_xor(d,8);
            n += __shfl_xor(n,1); n += __shfl_xor(n,2);
            n += __shfl_xor(n,4); n += __shfl_xor(n,8);
            if (lo16 == 0) {
                int t = (u>>2)*16 + quad*4 + (u&3);
                Dp[wave][t] = d; Np[wave][t] = n;
            }
        }
        #pragma unroll
        for (int cb2=0;cb2<4;cb2++) {
            float ss = 0.f;
            #pragma unroll
            for (int cm=0;cm<4;cm++)
                #pragma unroll
                for (int r=0;r<4;r++){ float v = wacc[cm][cb2][r]; ss += v*v; }
            ss += __shfl_xor(ss,16);
            ss += __shfl_xor(ss,32);
            if (quad==0) wn2P[wave][cb2>>1][cb2&1][lo16] = ss;
        }
        __syncthreads();

        if (tid < 64) {
            int i_f = tid >> 5, t = tid & 31;
            int nt2 = t >> 4, lo = t & 15;
            float w2 = wn2P[0][i_f][nt2][lo] + wn2P[1][i_f][nt2][lo]
                     + wn2P[2][i_f][nt2][lo] + wn2P[3][i_f][nt2][lo];
            float D = Dp[i_f*2][t] + Dp[i_f*2+1][t];
            float N = Np[i_f*2][t] + Np[i_f*2+1][t];
            int i_gf = ip*2 + i_f;
            float qv = W[WS_QN + i_gf*32 + t];
            float numS = N/D;
            float wnS = sqrtf(w2)/D;
            float v = G2c * (numS / fmaxf(qv*wnS, EPSF));
            float mx = v;
            for (int o=1;o<32;o<<=1) mx = fmaxf(mx, __shfl_xor(mx,o));
            float e = __expf(v-mx);
            for (int o=1;o<32;o<<=1) e += __shfl_xor(e,o);
            if (t==0) W[WS_SIM + i_gf*64 + j] = mx + __logf(e);
        }
    } else if (bid < 256) {
        // ================= moco (afr streamed: register diet) ===============
        int mu = bid >> 7, ch = bid & 127;
        const float* Q = mu ? queueIm : queue;
        const short* Abf = B16 + CNRN_OFF + mu*16384;

        float m16[16], s16[16];
        #pragma unroll
        for (int u=0;u<16;u++){ m16[u] = -1e30f; s16[u] = 0.f; }

        for (int t4 = 0; t4 < 2; t4++) {
            int colb = ch*128 + (wave*2 + t4)*16;
            float4v acc[4];
            #pragma unroll
            for (int mt=0;mt<4;mt++) acc[mt] = (float4v){0.f,0.f,0.f,0.f};
            for (int ks = 0; ks < 8; ks++) {
                short8 bfr;
                #pragma unroll
                for (int jj=0;jj<8;jj++) {
                    float bv = Q[(size_t)(ks*32 + quad*8 + jj)*KK + colb + lo16];
                    bfr[jj] = f2bf(bv);
                }
                #pragma unroll
                for (int mt=0;mt<4;mt++) {
                    short8 af = *(const short8*)(Abf + (mt*16+lo16)*256 + ks*32 + quad*8);
                    acc[mt] = mfma_bf16(af, bfr, acc[mt]);
                }
            }
            #pragma unroll
            for (int mt=0;mt<4;mt++)
                #pragma unroll
                for (int r=0;r<4;r++) {
                    float v = acc[mt][r]*INV_T;
                    int u = mt*4+r;
                    float nm = fmaxf(m16[u], v);
                    s16[u] = s16[u]*__expf(m16[u]-nm) + __expf(v-nm);
                    m16[u] = nm;
                }
        }
        #pragma unroll
        for (int u=0;u<16;u++) {
            #pragma unroll
            for (int o=1;o<16;o<<=1) {
                float om = __shfl_xor(m16[u],o), os = __shfl_xor(s16[u],o);
                float nm = fmaxf(m16[u],om);
                s16[u] = s16[u]*__expf(m16[u]-nm) + os*__expf(om-nm);
                m16[u] = nm;
            }
        }
        if (lo16 == 0) {
            #pragma unroll
            for (int u=0;u<16;u++) {
                int row = (u>>2)*16 + quad*4 + (u&3);
                redm[wave][row] = m16[u]; reds[wave][row] = s16[u];
            }
        }
        __syncthreads();
        if (tid < 64) {
            float m = redm[0][tid], s = reds[0][tid];
            for (int w=1;w<4;w++) {
                float om = redm[w][tid], os = reds[w][tid];
                float nm = fmaxf(m,om);
                s = s*__expf(m-nm) + os*__expf(om-nm);
                m = nm;
            }
            W[WS_PM + mu*8192 + ch*64 + tid] = m;
            W[WS_PS + mu*8192 + ch*64 + tid] = s;
        }
    } else {
        // ================= smat (+ moco diag dots) =================
        int i = bid - 256;
        sa0[tid] = W[WS_CN + i*256 + tid];
        sa1[tid] = W[WS_RN + i*256 + tid];
        __syncthreads();
        {
            float d0 = sa0[tid] * W[WS_RAN + i*256 + tid];
            float d1 = sa1[tid] * W[WS_CAN + i*256 + tid];
            for (int o=1;o<64;o<<=1){ d0 += __shfl_xor(d0,o); d1 += __shfl_xor(d1,o); }
            if (lane==0){ dred[0][wave]=d0; dred[1][wave]=d1; }
        }
        const float* B0 = W + WS_RN;
        const float* B1v = W + WS_RAN;
        float av0 = sa0[tid], av1 = sa1[tid];
        for (int jj = 0; jj < 64; jj++) {
            float v0 = av0 * B0[jj*256 + tid];
            float v1 = av1 * B1v[jj*256 + tid];
            for (int o=1;o<64;o<<=1){ v0 += __shfl_xor(v0,o); v1 += __shfl_xor(v1,o); }
            if (lane==0){ part[0][jj][wave]=v0; part[1][jj][wave]=v1; }
        }
        __syncthreads();
        if (tid < 128) {
            int mat = tid>>6, jj = tid&63;
            float s = part[mat][jj][0]+part[mat][jj][1]+part[mat][jj][2]+part[mat][jj][3];
            W[(mat? WS_S2 : WS_S0) + i*64 + jj] = G3c * s;
        } else if (tid == 128) {
            W[WS_DOT + i]      = dred[0][0]+dred[0][1]+dred[0][2]+dred[0][3];
        } else if (tid == 129) {
            W[WS_DOT + 64 + i] = dred[1][0]+dred[1][1]+dred[1][2]+dred[1][3];
        }
    }
}

// ---------------------------------------------------------------------------
// Final: all cross-entropies -> d_out[7] (R9 version)
// ---------------------------------------------------------------------------
__global__ __launch_bounds__(256) void final_kernel(
    const int* __restrict__ labels, float* __restrict__ W, float* __restrict__ out)
{
    int tid = threadIdx.x;
    __shared__ float mats[3][64][65];
    __shared__ float mmL[2][4][64], ssL[2][4][64];
    __shared__ float cearr[6][64];
    __shared__ float cemoco[128];

    for (int idx = tid; idx < 3*4096; idx += 256) {
        int t = idx >> 12, rem = idx & 4095;
        const float* src = W + (t==0 ? WS_SIM : (t==1 ? WS_S0 : WS_S2));
        mats[t][rem>>6][rem&63] = src[rem];
    }

    {
        int g = tid >> 6, r = tid & 63;
        for (int mu=0; mu<2; mu++) {
            float m = -1e30f, s = 0.f;
            for (int k=0; k<32; k++) {
                int ch = g*32 + k;
                float om = W[WS_PM + mu*8192 + ch*64 + r];
                float os = W[WS_PS + mu*8192 + ch*64 + r];
                float nm = fmaxf(m, om);
                s = s*__expf(m-nm) + os*__expf(om-nm);
                m = nm;
            }
            mmL[mu][g][r] = m; ssL[mu][g][r] = s;
        }
    }
    __syncthreads();

    if (tid < 128) {
        int mu = tid>>6, r = tid&63;
        float m = mmL[mu][0][r], s = ssL[mu][0][r];
        for (int g=1; g<4; g++) {
            float om = mmL[mu][g][r], os = ssL[mu][g][r];
            float nm = fmaxf(m, om);
            s = s*__expf(m-nm) + os*__expf(om-nm);
            m = nm;
        }
        float dot = W[WS_DOT + mu*64 + r];
        float v0 = dot*INV_T;
        float nm = fmaxf(m, v0);
        float S = s*__expf(m-nm) + __expf(v0-nm);
        cemoco[tid] = nm + __logf(S) - v0;
    }

    for (int pass=0; pass<2; pass++) {
        int cfg = pass*4 + (tid>>6);
        int row = tid&63;
        if (cfg < 6) {
            int mi; float scale; int colMajor;
            if (cfg==0){ mi=0; scale=G3c; colMajor=1; }
            else if (cfg==1){ mi=0; scale=G3c; colMajor=0; }
            else if (cfg==2){ mi=1; scale=1.f; colMajor=0; }
            else if (cfg==3){ mi=1; scale=1.f; colMajor=1; }
            else if (cfg==4){ mi=2; scale=1.f; colMajor=0; }
            else            { mi=2; scale=1.f; colMajor=1; }
            float mx = -1e30f;
            for (int x=0;x<64;x++) {
                float v = (colMajor? mats[mi][x][row] : mats[mi][row][x])*scale;
                mx = fmaxf(mx, v);
            }
            float se = 0.f;
            for (int x=0;x<64;x++) {
                float v = (colMajor? mats[mi][x][row] : mats[mi][row][x])*scale;
                se += __expf(v-mx);
            }
            int lbl = labels[row];
            float diag = (colMajor? mats[mi][lbl][row] : mats[mi][row][lbl])*scale;
            cearr[cfg][row] = mx + __logf(se) - diag;
        }
    }
    __syncthreads();

    if (tid < 7) {
        float r;
        if (tid == 4) {
            float s0=0.f, s1=0.f;
            for (int k=0;k<64;k++){ s0 += cemoco[k]; s1 += cemoco[64+k]; }
            r = (s0/64.f + s1/64.f)*0.5f;
        } else {
            int cfg = (tid < 4) ? tid : tid - 1;
            float s = 0.f;
            for (int k=0;k<64;k++) s += cearr[cfg][k];
            r = s/64.f;
        }
        out[tid] = r;
    }
}

// ---------------------------------------------------------------------------
extern "C" void kernel_launch(void* const* d_in, const int* in_sizes, int n_in,
                              void* d_out, int out_size, void* d_ws, size_t ws_size,
                              hipStream_t stream)
{
    const float* cnn   = (const float*)d_in[0];
    const float* rnn   = (const float*)d_in[1];
    const float* img   = (const float*)d_in[2];
    const float* wemb  = (const float*)d_in[3];
    const float* cnnA  = (const float*)d_in[4];
    const float* rnnA  = (const float*)d_in[5];
    const float* queue   = (const float*)d_in[6];
    const float* queueIm = (const float*)d_in[7];
    const int*   labels  = (const int*)d_in[9];
    float* W   = (float*)d_ws;
    float* out = (float*)d_out;

    prep_kernel<<<1664, 256, 0, stream>>>(cnn, rnn, img, wemb, cnnA, rnnA, W);
    attn_moco_kernel<<<2368, 256, 0, stream>>>(queue, queueIm, W);
    final_kernel<<<1, 256, 0, stream>>>(labels, W, out);
}

// Round 12
// 220.882 us; speedup vs baseline: 1.3575x; 1.3575x over previous
//
#include <hip/hip_runtime.h>
#include <hip/hip_bf16.h>
#include <math.h>

#define BB   64
#define TT   32
#define CC   256
#define KK   16384
#define G1c  4.0f
#define G2c  5.0f
#define G3c  10.0f
#define INV_T 20.0f
#define EPSF 1e-8f

// Workspace layout (floats)
#define WS_SIM 0
#define WS_S0  4096
#define WS_S2  8192
#define WS_CN  12288
#define WS_RN  28672
#define WS_CAN 45056
#define WS_RAN 61440
#define WS_QN  77824
#define WS_PM  79872                 // [2][128 ch][64 row]
#define WS_PS  (WS_PM + 16384)
#define WS_CNT  (WS_PS + 16384)      // reused: [2][64] moco diag dots
#define WS_RNT  (WS_CNT + 16384)
#define WS_CANT (WS_RNT + 16384)
#define WS_RANT (WS_CANT + 16384)
#define WS_F32_TOTAL (WS_RANT + 16384)
#define WS_DOT  WS_CNT               // dot_it[64] then dot_ti[64]

// bf16 arrays (shorts), after the f32 section
// ctxT layout: [j][tile(10)][8192 shorts]; within a tile the 32x256 (s,c)
// block is subtiled+swizzled:
//   L  = (s4*16 + c16)*64 + r4*16 + cc        (s = s4*4+r4, c = c16*16+cc)
//   L' = L ^ ((s4&3)<<4) ^ (((c16&1)^(s4&1))<<3)
// -> attn staging is an identity copy (global_load_lds-compatible),
//    scores reads are conflict-free ds_read_b128, wa via ds_read_b64_tr_b16.
#define CTXT_ELEMS (64*320*256)
#define WQ_ELEMS   (64*32*256)     // wq[i][t][c]
#define WQ_OFF     CTXT_ELEMS
#define CNRN_OFF   (CTXT_ELEMS + WQ_ELEMS)   // [2][64][256]

typedef __attribute__((ext_vector_type(8))) short short8;
typedef __attribute__((ext_vector_type(4))) short short4v;
typedef __attribute__((ext_vector_type(4))) float float4v;

__device__ __forceinline__ float4v mfma_bf16(short8 a, short8 b, float4v c) {
    return __builtin_amdgcn_mfma_f32_16x16x32_bf16(a, b, c, 0, 0, 0);
}

__device__ __forceinline__ short f2bf(float f) {
    union { float f; unsigned u; } x; x.f = f;
    unsigned r = x.u + 0x7FFFu + ((x.u >> 16) & 1u);
    return (short)(r >> 16);
}

// involutive swizzle on 13-bit tile-local short index
__device__ __forceinline__ int swz13(int L) {
    return L ^ (((L>>10)&3)<<4) ^ ((((L>>6)&1) ^ ((L>>10)&1))<<3);
}

// async global->LDS: one wave stages 4KB (4 calls x 64 lanes x 16B).
__device__ __forceinline__ void stage_tile(const short* g, short* l) {
    #pragma unroll
    for (int m = 0; m < 4; m++)
        __builtin_amdgcn_global_load_lds(
            (const __attribute__((address_space(1))) unsigned int*)(g + m*512),
            (__attribute__((address_space(3))) unsigned int*)(l + m*512),
            16, 0, 0);
}

// ---------------------------------------------------------------------------
// Prep. grid: [0,256) codes | [256,320) qn | [320,1600) ctxT | [1600,1664) wq
// ---------------------------------------------------------------------------
__global__ __launch_bounds__(256) void prep_kernel(
    const float* __restrict__ cnn, const float* __restrict__ rnn,
    const float* __restrict__ img, const float* __restrict__ wemb,
    const float* __restrict__ cnnA, const float* __restrict__ rnnA,
    float* __restrict__ W)
{
    int bid = blockIdx.x, tid = threadIdx.x;
    short* B16 = (short*)(W + WS_F32_TOTAL);
    short* ctxT = B16;
    short* wq   = B16 + WQ_OFF;
    short* cnrn = B16 + CNRN_OFF;

    if (bid < 256) {
        int mat = bid >> 6, row = bid & 63;
        const float* src = (mat==0)? cnn : (mat==1)? rnn : (mat==2)? cnnA : rnnA;
        float* dst  = W + ((mat==0)? WS_CN  : (mat==1)? WS_RN  : (mat==2)? WS_CAN  : WS_RAN);
        float v = src[row*256 + tid];
        float ss = v*v;
        for (int o=1;o<64;o<<=1) ss += __shfl_xor(ss,o);
        __shared__ float sc[4];
        if ((tid&63)==0) sc[tid>>6] = ss;
        __syncthreads();
        float tot = sc[0]+sc[1]+sc[2]+sc[3];
        float inv = 1.0f / fmaxf(sqrtf(tot), EPSF);
        float nv = v*inv;
        dst[row*256+tid] = nv;
        if (mat < 2) cnrn[(mat*64+row)*256 + tid] = f2bf(nv);
    } else if (bid < 320) {
        int i = bid - 256;
        int t = tid >> 3, k = tid & 7;
        const float4* wp = (const float4*)(wemb + (i*32 + t)*256 + k*32);
        float ss = 0.f;
        #pragma unroll
        for (int c4=0;c4<8;c4++){
            float4 v = wp[c4];
            ss += v.x*v.x + v.y*v.y + v.z*v.z + v.w*v.w;
        }
        ss += __shfl_xor(ss,1); ss += __shfl_xor(ss,2); ss += __shfl_xor(ss,4);
        if (k==0) W[WS_QN + i*32 + t] = sqrtf(ss);
    } else if (bid < 1600) {
        // ctxT subtiled+swizzled bf16, s padded to 320 (zeros for s>=289)
        int b3 = bid - 320; int j = b3 / 20, mt20 = b3 % 20;
        int half = mt20 & 1;
        int s0 = mt20 * 16;
        __shared__ float tbuf[16*257];
        #pragma unroll
        for (int it=0; it<16; it++) {
            int idx = tid + it*256;
            int c = idx >> 4, sl = idx & 15, s = s0 + sl;
            float v = (s < 289) ? img[((size_t)(j*256 + c))*289 + s] : 0.0f;
            tbuf[sl*257 + c] = v;
        }
        __syncthreads();
        short* dst = ctxT + (size_t)j*81920 + (size_t)mt20*4096;
        #pragma unroll
        for (int it=0; it<4; it++) {
            int idx4 = tid + it*256;
            int v = half*4096 + idx4*4;
            int L = swz13(v);
            int sl = ((L>>10)&3)*4 + ((L>>4)&3);
            int c  = ((L>>6)&15)*16 + (L&15);
            const float* tb = &tbuf[sl*257 + c];
            short4v o = { f2bf(tb[0]), f2bf(tb[1]), f2bf(tb[2]), f2bf(tb[3]) };
            *(short4v*)(dst + idx4*4) = o;
        }
    } else {
        // wq: bf16 convert, vectorized (8 grid-stride iterations)
        const float4* src4 = (const float4*)wemb;
        for (int idx = (bid-1600)*256 + tid; idx < WQ_ELEMS/4; idx += 64*256) {
            float4 v = src4[idx];
            short4v o = { f2bf(v.x), f2bf(v.y), f2bf(v.z), f2bf(v.w) };
            *(short4v*)(wq + idx*4) = o;
        }
    }
}

// ---------------------------------------------------------------------------
// Fused moco + smat + attn (R9 best-verified structure).
// bid < 256: moco; [256,320): smat (+ diag dots); >= 320: attention (R6 loop).
// ---------------------------------------------------------------------------
__global__ __launch_bounds__(256, 2) void attn_moco_kernel(
    const float* __restrict__ queue, const float* __restrict__ queueIm,
    float* __restrict__ W)
{
    __shared__ __align__(16) short ctx_sc[3][8192];         // 48 KB (3-buf)
    __shared__ __align__(16) short eTile[2][2][32][40];     // 10240 B (dbuf)
    __shared__ float Dp[4][32], Np[4][32];
    __shared__ float wn2P[4][2][2][16];
    __shared__ float redm[4][64], reds[4][64];     // moco
    __shared__ float sa0[256], sa1[256];           // smat
    __shared__ float part[2][64][4];
    __shared__ float dred[2][4];

    int bid = blockIdx.x, tid = threadIdx.x;
    int lane = tid & 63, wave = tid >> 6;
    int lo16 = lane & 15, quad = lane >> 4;

    const short* B16 = (const short*)(W + WS_F32_TOTAL);

    if (bid >= 320) {
        // ================= attention =================
        const short* ctxT = B16;
        const short* wq   = B16 + WQ_OFF;

        int abid0 = bid - 320;
        int abid = (abid0 & 7)*256 + (abid0 >> 3);
        int j = abid >> 5, ip = abid & 31;
        int i_l = wave >> 1, mt = wave & 1;
        int i_g = ip*2 + i_l;

        short8 bq[2][8];
        {
            const short* p = wq + i_g*8192;
            #pragma unroll
            for (int nt2=0;nt2<2;nt2++)
                #pragma unroll
                for (int kk=0;kk<8;kk++)
                    bq[nt2][kk] = *(const short8*)(p + (nt2*16+lo16)*256 + kk*32 + quad*8);
        }

        float4v wacc[4][4];
        #pragma unroll
        for (int cm=0;cm<4;cm++)
            #pragma unroll
            for (int cb2=0;cb2<4;cb2++) wacc[cm][cb2] = (float4v){0.f,0.f,0.f,0.f};
        float D8[8], N8[8];
        #pragma unroll
        for (int u=0;u<8;u++){ D8[u]=0.f; N8[u]=0.f; }

        const short* ctxTj = ctxT + (size_t)j * 81920;

        int s4p = lo16 >> 2;
        int qh = quad >> 1, ql = quad & 1;
        int Lb = (mt*4 + s4p)*1024 + qh*64
               + (((lo16&3) ^ s4p) << 4)
               + ((ql ^ qh ^ (s4p&1)) << 3);
        int pcol = mt*16 + (lo16 & 12) + ((lo16 & 3) ^ s4p);
        unsigned trbase = (unsigned)(unsigned long long)(const void*)(&ctx_sc[0][0])
                        + (unsigned)(quad*4096 + wave*512 + lo16*2);

        #define SOFTMAX_TILE(AK0, AK1, KTILE)                                  \
        {                                                                      \
            float mx = fmaxf(fmaxf(fmaxf((AK0)[0],(AK0)[1]), fmaxf((AK0)[2],(AK0)[3])), \
                             fmaxf(fmaxf((AK1)[0],(AK1)[1]), fmaxf((AK1)[2],(AK1)[3]))); \
            mx = fmaxf(mx, __shfl_xor(mx,16));                                 \
            mx = fmaxf(mx, __shfl_xor(mx,32));                                 \
            float e0[4], e1[4]; float z = 0.f;                                 \
            _Pragma("unroll")                                                  \
            for (int r=0;r<4;r++) {                                            \
                e0[r] = __expf((AK0)[r]-mx); e1[r] = __expf((AK1)[r]-mx);      \
                z += e0[r] + e1[r];                                            \
            }                                                                  \
            z += __shfl_xor(z,16); z += __shfl_xor(z,32);                      \
            float grinv = G1c / z;                                             \
            int sg = (KTILE)*32 + mt*16 + lo16;                                \
            short* et = &eTile[(KTILE)&1][i_l][0][0];                          \
            _Pragma("unroll")                                                  \
            for (int r=0;r<4;r++) {                                            \
                float ev0 = __expf(e0[r]*grinv);                               \
                float ev1 = __expf(e1[r]*grinv);                               \
                if (sg < 289) {                                                \
                    D8[r]   += ev0; N8[r]   += ev0*(AK0)[r];                   \
                    D8[4+r] += ev1; N8[4+r] += ev1*(AK1)[r];                   \
                }                                                              \
                et[(quad*4+r)*40 + pcol]    = f2bf(ev0);                       \
                et[(16+quad*4+r)*40 + pcol] = f2bf(ev1);                       \
            }                                                                  \
        }

        stage_tile(ctxTj + 0*8192 + wave*2048 + lane*8, &ctx_sc[0][wave*2048]);
        stage_tile(ctxTj + 1*8192 + wave*2048 + lane*8, &ctx_sc[1][wave*2048]);
        stage_tile(ctxTj + 2*8192 + wave*2048 + lane*8, &ctx_sc[2][wave*2048]);
        asm volatile("s_waitcnt vmcnt(8)\n\ts_barrier" ::: "memory");
        __builtin_amdgcn_sched_barrier(0);

        // peeled k=0
        {
            float4v a0 = {0.f,0.f,0.f,0.f}, a1 = {0.f,0.f,0.f,0.f};
            const short* score_base = &ctx_sc[0][0] + Lb;
            #pragma unroll
            for (int kk=0;kk<8;kk++) {
                short8 cf = *(const short8*)(score_base + kk*128);
                a0 = mfma_bf16(bq[0][kk], cf, a0);
                a1 = mfma_bf16(bq[1][kk], cf, a1);
            }
            SOFTMAX_TILE(a0, a1, 0)
        }
        asm volatile("s_waitcnt vmcnt(4) lgkmcnt(0)\n\ts_barrier" ::: "memory");
        __builtin_amdgcn_sched_barrier(0);

        int cb = 1, cbm1 = 0;
        for (int k = 1; k <= 9; ++k) {
            float4v a0 = {0.f,0.f,0.f,0.f}, a1 = {0.f,0.f,0.f,0.f};
            {
                const short* score_base = &ctx_sc[cb][0] + Lb;
                #pragma unroll
                for (int kk=0;kk<8;kk++) {
                    short8 cf = *(const short8*)(score_base + kk*128);
                    a0 = mfma_bf16(bq[0][kk], cf, a0);
                    a1 = mfma_bf16(bq[1][kk], cf, a1);
                }
            }
            unsigned trA = trbase + (unsigned)(cbm1*16384);
            unsigned trB = trA ^ 16u;
            short4v w00,w01,w10,w11,w20,w21,w30,w31;
            asm volatile("ds_read_b64_tr_b16 %0, %1 offset:0"    : "=v"(w00) : "v"(trA));
            asm volatile("ds_read_b64_tr_b16 %0, %1 offset:2048" : "=v"(w01) : "v"(trB));
            asm volatile("ds_read_b64_tr_b16 %0, %1 offset:128"  : "=v"(w10) : "v"(trB));
            asm volatile("ds_read_b64_tr_b16 %0, %1 offset:2176" : "=v"(w11) : "v"(trA));
            asm volatile("ds_read_b64_tr_b16 %0, %1 offset:256"  : "=v"(w20) : "v"(trA));
            asm volatile("ds_read_b64_tr_b16 %0, %1 offset:2304" : "=v"(w21) : "v"(trB));
            asm volatile("ds_read_b64_tr_b16 %0, %1 offset:384"  : "=v"(w30) : "v"(trB));
            asm volatile("ds_read_b64_tr_b16 %0, %1 offset:2432" : "=v"(w31) : "v"(trA));
            int ebp = (k-1) & 1;
            const short8 bf00 = *(const short8*)&eTile[ebp][0][lo16][quad*8];
            const short8 bf01 = *(const short8*)&eTile[ebp][0][16+lo16][quad*8];
            const short8 bf10 = *(const short8*)&eTile[ebp][1][lo16][quad*8];
            const short8 bf11 = *(const short8*)&eTile[ebp][1][16+lo16][quad*8];
            asm volatile("s_waitcnt lgkmcnt(0)" ::: "memory");
            __builtin_amdgcn_sched_barrier(0);
            {
                short8 wa0_ = {w00[0],w00[1],w00[2],w00[3], w01[0],w01[1],w01[2],w01[3]};
                short8 wa1_ = {w10[0],w10[1],w10[2],w10[3], w11[0],w11[1],w11[2],w11[3]};
                short8 wa2_ = {w20[0],w20[1],w20[2],w20[3], w21[0],w21[1],w21[2],w21[3]};
                short8 wa3_ = {w30[0],w30[1],w30[2],w30[3], w31[0],w31[1],w31[2],w31[3]};
                wacc[0][0] = mfma_bf16(wa0_, bf00, wacc[0][0]);
                wacc[0][1] = mfma_bf16(wa0_, bf01, wacc[0][1]);
                wacc[0][2] = mfma_bf16(wa0_, bf10, wacc[0][2]);
                wacc[0][3] = mfma_bf16(wa0_, bf11, wacc[0][3]);
                wacc[1][0] = mfma_bf16(wa1_, bf00, wacc[1][0]);
                wacc[1][1] = mfma_bf16(wa1_, bf01, wacc[1][1]);
                wacc[1][2] = mfma_bf16(wa1_, bf10, wacc[1][2]);
                wacc[1][3] = mfma_bf16(wa1_, bf11, wacc[1][3]);
                wacc[2][0] = mfma_bf16(wa2_, bf00, wacc[2][0]);
                wacc[2][1] = mfma_bf16(wa2_, bf01, wacc[2][1]);
                wacc[2][2] = mfma_bf16(wa2_, bf10, wacc[2][2]);
                wacc[2][3] = mfma_bf16(wa2_, bf11, wacc[2][3]);
                wacc[3][0] = mfma_bf16(wa3_, bf00, wacc[3][0]);
                wacc[3][1] = mfma_bf16(wa3_, bf01, wacc[3][1]);
                wacc[3][2] = mfma_bf16(wa3_, bf10, wacc[3][2]);
                wacc[3][3] = mfma_bf16(wa3_, bf11, wacc[3][3]);
            }
            SOFTMAX_TILE(a0, a1, k)
            asm volatile("s_waitcnt vmcnt(0) lgkmcnt(0)\n\ts_barrier" ::: "memory");
            __builtin_amdgcn_sched_barrier(0);
            if (k < 8)
                stage_tile(ctxTj + (k+2)*8192 + wave*2048 + lane*8,
                           &ctx_sc[cbm1][wave*2048]);
            cbm1 = cb; cb = (cb==2)?0:cb+1;
        }

        // epilogue: wC(9)
        {
            unsigned trA = trbase + (unsigned)(cbm1*16384);
            unsigned trB = trA ^ 16u;
            short4v w00,w01,w10,w11,w20,w21,w30,w31;
            asm volatile("ds_read_b64_tr_b16 %0, %1 offset:0"    : "=v"(w00) : "v"(trA));
            asm volatile("ds_read_b64_tr_b16 %0, %1 offset:2048" : "=v"(w01) : "v"(trB));
            asm volatile("ds_read_b64_tr_b16 %0, %1 offset:128"  : "=v"(w10) : "v"(trB));
            asm volatile("ds_read_b64_tr_b16 %0, %1 offset:2176" : "=v"(w11) : "v"(trA));
            asm volatile("ds_read_b64_tr_b16 %0, %1 offset:256"  : "=v"(w20) : "v"(trA));
            asm volatile("ds_read_b64_tr_b16 %0, %1 offset:2304" : "=v"(w21) : "v"(trB));
            asm volatile("ds_read_b64_tr_b16 %0, %1 offset:384"  : "=v"(w30) : "v"(trB));
            asm volatile("ds_read_b64_tr_b16 %0, %1 offset:2432" : "=v"(w31) : "v"(trA));
            const short8 bf00 = *(const short8*)&eTile[1][0][lo16][quad*8];
            const short8 bf01 = *(const short8*)&eTile[1][0][16+lo16][quad*8];
            const short8 bf10 = *(const short8*)&eTile[1][1][lo16][quad*8];
            const short8 bf11 = *(const short8*)&eTile[1][1][16+lo16][quad*8];
            asm volatile("s_waitcnt lgkmcnt(0)" ::: "memory");
            __builtin_amdgcn_sched_barrier(0);
            short8 wa0_ = {w00[0],w00[1],w00[2],w00[3], w01[0],w01[1],w01[2],w01[3]};
            short8 wa1_ = {w10[0],w10[1],w10[2],w10[3], w11[0],w11[1],w11[2],w11[3]};
            short8 wa2_ = {w20[0],w20[1],w20[2],w20[3], w21[0],w21[1],w21[2],w21[3]};
            short8 wa3_ = {w30[0],w30[1],w30[2],w30[3], w31[0],w31[1],w31[2],w31[3]};
            wacc[0][0] = mfma_bf16(wa0_, bf00, wacc[0][0]);
            wacc[0][1] = mfma_bf16(wa0_, bf01, wacc[0][1]);
            wacc[0][2] = mfma_bf16(wa0_, bf10, wacc[0][2]);
            wacc[0][3] = mfma_bf16(wa0_, bf11, wacc[0][3]);
            wacc[1][0] = mfma_bf16(wa1_, bf00, wacc[1][0]);
            wacc[1][1] = mfma_bf16(wa1_, bf01, wacc[1][1]);
            wacc[1][2] = mfma_bf16(wa1_, bf10, wacc[1][2]);
            wacc[1][3] = mfma_bf16(wa1_, bf11, wacc[1][3]);
            wacc[2][0] = mfma_bf16(wa2_, bf00, wacc[2][0]);
            wacc[2][1] = mfma_bf16(wa2_, bf01, wacc[2][1]);
            wacc[2][2] = mfma_bf16(wa2_, bf10, wacc[2][2]);
            wacc[2][3] = mfma_bf16(wa2_, bf11, wacc[2][3]);
            wacc[3][0] = mfma_bf16(wa3_, bf00, wacc[3][0]);
            wacc[3][1] = mfma_bf16(wa3_, bf01, wacc[3][1]);
            wacc[3][2] = mfma_bf16(wa3_, bf10, wacc[3][2]);
            wacc[3][3] = mfma_bf16(wa3_, bf11, wacc[3][3]);
        }
        #undef SOFTMAX_TILE

        #pragma unroll
        for (int u=0;u<8;u++) {
            float d = D8[u], n = N8[u];
            d += __shfl_xor(d,1); d += __shfl_xor(d,2);
            d += __shfl_xor(d,4); d += __shfl_xor(d,8);
            n += __shfl_xor(n,1); n += __shfl_xor(n,2);
            n += __shfl_xor(n,4); n += __shfl_xor(n,8);
            if (lo16 == 0) {
                int t = (u>>2)*16 + quad*4 + (u&3);
                Dp[wave][t] = d; Np[wave][t] = n;
            }
        }
        #pragma unroll
        for (int cb2=0;cb2<4;cb2++) {
            float ss = 0.f;
            #pragma unroll
            for (int cm=0;cm<4;cm++)
                #pragma unroll
                for (int r=0;r<4;r++){ float v = wacc[cm][cb2][r]; ss += v*v; }
            ss += __shfl_xor(ss,16);
            ss += __shfl_xor(ss,32);
            if (quad==0) wn2P[wave][cb2>>1][cb2&1][lo16] = ss;
        }
        __syncthreads();

        if (tid < 64) {
            int i_f = tid >> 5, t = tid & 31;
            int nt2 = t >> 4, lo = t & 15;
            float w2 = wn2P[0][i_f][nt2][lo] + wn2P[1][i_f][nt2][lo]
                     + wn2P[2][i_f][nt2][lo] + wn2P[3][i_f][nt2][lo];
            float D = Dp[i_f*2][t] + Dp[i_f*2+1][t];
            float N = Np[i_f*2][t] + Np[i_f*2+1][t];
            int i_gf = ip*2 + i_f;
            float qv = W[WS_QN + i_gf*32 + t];
            float numS = N/D;
            float wnS = sqrtf(w2)/D;
            float v = G2c * (numS / fmaxf(qv*wnS, EPSF));
            float mx = v;
            for (int o=1;o<32;o<<=1) mx = fmaxf(mx, __shfl_xor(mx,o));
            float e = __expf(v-mx);
            for (int o=1;o<32;o<<=1) e += __shfl_xor(e,o);
            if (t==0) W[WS_SIM + i_gf*64 + j] = mx + __logf(e);
        }
    } else if (bid < 256) {
        // ================= moco =================
        int mu = bid >> 7, ch = bid & 127;
        const float* Q = mu ? queueIm : queue;
        const short* Abf = B16 + CNRN_OFF + mu*16384;

        short8 afr[4][8];
        #pragma unroll
        for (int mt=0;mt<4;mt++)
            #pragma unroll
            for (int kk=0;kk<8;kk++)
                afr[mt][kk] = *(const short8*)(Abf + (mt*16+lo16)*256 + kk*32 + quad*8);

        float m16[16], s16[16];
        #pragma unroll
        for (int u=0;u<16;u++){ m16[u] = -1e30f; s16[u] = 0.f; }

        for (int t4 = 0; t4 < 2; t4++) {
            int colb = ch*128 + (wave*2 + t4)*16;
            float4v acc[4];
            #pragma unroll
            for (int mt=0;mt<4;mt++) acc[mt] = (float4v){0.f,0.f,0.f,0.f};
            for (int ks = 0; ks < 8; ks++) {
                short8 bfr;
                #pragma unroll
                for (int jj=0;jj<8;jj++) {
                    float bv = Q[(size_t)(ks*32 + quad*8 + jj)*KK + colb + lo16];
                    bfr[jj] = f2bf(bv);
                }
                #pragma unroll
                for (int mt=0;mt<4;mt++) acc[mt] = mfma_bf16(afr[mt][ks], bfr, acc[mt]);
            }
            #pragma unroll
            for (int mt=0;mt<4;mt++)
                #pragma unroll
                for (int r=0;r<4;r++) {
                    float v = acc[mt][r]*INV_T;
                    int u = mt*4+r;
                    float nm = fmaxf(m16[u], v);
                    s16[u] = s16[u]*__expf(m16[u]-nm) + __expf(v-nm);
                    m16[u] = nm;
                }
        }
        #pragma unroll
        for (int u=0;u<16;u++) {
            #pragma unroll
            for (int o=1;o<16;o<<=1) {
                float om = __shfl_xor(m16[u],o), os = __shfl_xor(s16[u],o);
                float nm = fmaxf(m16[u],om);
                s16[u] = s16[u]*__expf(m16[u]-nm) + os*__expf(om-nm);
                m16[u] = nm;
            }
        }
        if (lo16 == 0) {
            #pragma unroll
            for (int u=0;u<16;u++) {
                int row = (u>>2)*16 + quad*4 + (u&3);
                redm[wave][row] = m16[u]; reds[wave][row] = s16[u];
            }
        }
        __syncthreads();
        if (tid < 64) {
            float m = redm[0][tid], s = reds[0][tid];
            for (int w=1;w<4;w++) {
                float om = redm[w][tid], os = reds[w][tid];
                float nm = fmaxf(m,om);
                s = s*__expf(m-nm) + os*__expf(om-nm);
                m = nm;
            }
            W[WS_PM + mu*8192 + ch*64 + tid] = m;
            W[WS_PS + mu*8192 + ch*64 + tid] = s;
        }
    } else {
        // ================= smat (+ moco diag dots) =================
        int i = bid - 256;
        sa0[tid] = W[WS_CN + i*256 + tid];
        sa1[tid] = W[WS_RN + i*256 + tid];
        __syncthreads();
        {
            float d0 = sa0[tid] * W[WS_RAN + i*256 + tid];
            float d1 = sa1[tid] * W[WS_CAN + i*256 + tid];
            for (int o=1;o<64;o<<=1){ d0 += __shfl_xor(d0,o); d1 += __shfl_xor(d1,o); }
            if (lane==0){ dred[0][wave]=d0; dred[1][wave]=d1; }
        }
        const float* B0 = W + WS_RN;
        const float* B1v = W + WS_RAN;
        float av0 = sa0[tid], av1 = sa1[tid];
        for (int jj = 0; jj < 64; jj++) {
            float v0 = av0 * B0[jj*256 + tid];
            float v1 = av1 * B1v[jj*256 + tid];
            for (int o=1;o<64;o<<=1){ v0 += __shfl_xor(v0,o); v1 += __shfl_xor(v1,o); }
            if (lane==0){ part[0][jj][wave]=v0; part[1][jj][wave]=v1; }
        }
        __syncthreads();
        if (tid < 128) {
            int mat = tid>>6, jj = tid&63;
            float s = part[mat][jj][0]+part[mat][jj][1]+part[mat][jj][2]+part[mat][jj][3];
            W[(mat? WS_S2 : WS_S0) + i*64 + jj] = G3c * s;
        } else if (tid == 128) {
            W[WS_DOT + i]      = dred[0][0]+dred[0][1]+dred[0][2]+dred[0][3];
        } else if (tid == 129) {
            W[WS_DOT + 64 + i] = dred[1][0]+dred[1][1]+dred[1][2]+dred[1][3];
        }
    }
}

// ---------------------------------------------------------------------------
// Final: all cross-entropies -> d_out[7]
// ---------------------------------------------------------------------------
__global__ __launch_bounds__(256) void final_kernel(
    const int* __restrict__ labels, float* __restrict__ W, float* __restrict__ out)
{
    int tid = threadIdx.x;
    __shared__ float mats[3][64][65];
    __shared__ float mmL[2][4][64], ssL[2][4][64];
    __shared__ float cearr[6][64];
    __shared__ float cemoco[128];

    for (int idx = tid; idx < 3*4096; idx += 256) {
        int t = idx >> 12, rem = idx & 4095;
        const float* src = W + (t==0 ? WS_SIM : (t==1 ? WS_S0 : WS_S2));
        mats[t][rem>>6][rem&63] = src[rem];
    }

    {
        int g = tid >> 6, r = tid & 63;
        for (int mu=0; mu<2; mu++) {
            float m = -1e30f, s = 0.f;
            for (int k=0; k<32; k++) {
                int ch = g*32 + k;
                float om = W[WS_PM + mu*8192 + ch*64 + r];
                float os = W[WS_PS + mu*8192 + ch*64 + r];
                float nm = fmaxf(m, om);
                s = s*__expf(m-nm) + os*__expf(om-nm);
                m = nm;
            }
            mmL[mu][g][r] = m; ssL[mu][g][r] = s;
        }
    }
    __syncthreads();

    if (tid < 128) {
        int mu = tid>>6, r = tid&63;
        float m = mmL[mu][0][r], s = ssL[mu][0][r];
        for (int g=1; g<4; g++) {
            float om = mmL[mu][g][r], os = ssL[mu][g][r];
            float nm = fmaxf(m, om);
            s = s*__expf(m-nm) + os*__expf(om-nm);
            m = nm;
        }
        float dot = W[WS_DOT + mu*64 + r];
        float v0 = dot*INV_T;
        float nm = fmaxf(m, v0);
        float S = s*__expf(m-nm) + __expf(v0-nm);
        cemoco[tid] = nm + __logf(S) - v0;
    }

    for (int pass=0; pass<2; pass++) {
        int cfg = pass*4 + (tid>>6);
        int row = tid&63;
        if (cfg < 6) {
            int mi; float scale; int colMajor;
            if (cfg==0){ mi=0; scale=G3c; colMajor=1; }
            else if (cfg==1){ mi=0; scale=G3c; colMajor=0; }
            else if (cfg==2){ mi=1; scale=1.f; colMajor=0; }
            else if (cfg==3){ mi=1; scale=1.f; colMajor=1; }
            else if (cfg==4){ mi=2; scale=1.f; colMajor=0; }
            else            { mi=2; scale=1.f; colMajor=1; }
            float mx = -1e30f;
            for (int x=0;x<64;x++) {
                float v = (colMajor? mats[mi][x][row] : mats[mi][row][x])*scale;
                mx = fmaxf(mx, v);
            }
            float se = 0.f;
            for (int x=0;x<64;x++) {
                float v = (colMajor? mats[mi][x][row] : mats[mi][row][x])*scale;
                se += __expf(v-mx);
            }
            int lbl = labels[row];
            float diag = (colMajor? mats[mi][lbl][row] : mats[mi][row][lbl])*scale;
            cearr[cfg][row] = mx + __logf(se) - diag;
        }
    }
    __syncthreads();

    if (tid < 7) {
        float r;
        if (tid == 4) {
            float s0=0.f, s1=0.f;
            for (int k=0;k<64;k++){ s0 += cemoco[k]; s1 += cemoco[64+k]; }
            r = (s0/64.f + s1/64.f)*0.5f;
        } else {
            int cfg = (tid < 4) ? tid : tid - 1;
            float s = 0.f;
            for (int k=0;k<64;k++) s += cearr[cfg][k];
            r = s/64.f;
        }
        out[tid] = r;
    }
}

// ---------------------------------------------------------------------------
extern "C" void kernel_launch(void* const* d_in, const int* in_sizes, int n_in,
                              void* d_out, int out_size, void* d_ws, size_t ws_size,
                              hipStream_t stream)
{
    const float* cnn   = (const float*)d_in[0];
    const float* rnn   = (const float*)d_in[1];
    const float* img   = (const float*)d_in[2];
    const float* wemb  = (const float*)d_in[3];
    const float* cnnA  = (const float*)d_in[4];
    const float* rnnA  = (const float*)d_in[5];
    const float* queue   = (const float*)d_in[6];
    const float* queueIm = (const float*)d_in[7];
    const int*   labels  = (const int*)d_in[9];
    float* W   = (float*)d_ws;
    float* out = (float*)d_out;

    prep_kernel<<<1664, 256, 0, stream>>>(cnn, rnn, img, wemb, cnnA, rnnA, W);
    attn_moco_kernel<<<2368, 256, 0, stream>>>(queue, queueIm, W);
    final_kernel<<<1, 256, 0, stream>>>(labels, W, out);
}